// Round 1
// baseline (135.622 us; speedup 1.0000x reference)
//
#include <hip/hip_runtime.h>
#include <math.h>

// Problem constants (from setup_inputs)
constexpr int B = 8, N = 65536, C = 80, M = 64;
constexpr float F_ALPHA = 0.25f;
constexpr float F_EPS = 1e-4f;
constexpr float F_BETA = 1.0f / 9.0f;

__device__ __forceinline__ float waveReduceSum(float v) {
    #pragma unroll
    for (int off = 32; off > 0; off >>= 1) v += __shfl_down(v, off, 64);
    return v;
}

// -------------------- Kernel 1: anchor assignment + reg loss --------------------
// grid: (N/256, B), block: 256
__global__ __launch_bounds__(256) void assign_kernel(
    const float* __restrict__ anchors,   // [N,4] (anchors[0] of (1,N,4))
    const float* __restrict__ regs,      // [B,N,4]
    const float* __restrict__ ann,       // [B,M,5]
    signed char* __restrict__ labels,    // [B*N] out: pos->class, neg->-2, ignore->-1
    float* __restrict__ accum)           // [0..7]=num_pos, [8..15]=reg_sum, [16..23]=cls_sum
{
    const int b = blockIdx.y;
    const int n = blockIdx.x * 256 + threadIdx.x;

    __shared__ float bx1[M], by1[M], bx2[M], by2[M], barea[M], blab[M];
    if (threadIdx.x < M) {
        const int j = threadIdx.x;
        const float* a = ann + (size_t)(b * M + j) * 5;
        float x1 = a[0], y1 = a[1], x2 = a[2], y2 = a[3], lb = a[4];
        bx1[j] = x1; by1[j] = y1; bx2[j] = x2; by2[j] = y2;
        barea[j] = (x2 - x1) * (y2 - y1);
        blab[j] = lb;
    }
    __syncthreads();

    const float4 av = reinterpret_cast<const float4*>(anchors)[n];
    const float ax1 = av.x, ay1 = av.y, ax2 = av.z, ay2 = av.w;
    const float aarea = (ax2 - ax1) * (ay2 - ay1);

    float best = -2.0f;
    int bestj = 0;
    #pragma unroll 8
    for (int j = 0; j < M; ++j) {
        float iw = fminf(ax2, bx2[j]) - fmaxf(ax1, bx1[j]);
        float ih = fminf(ay2, by2[j]) - fmaxf(ay1, by1[j]);
        iw = fmaxf(iw, 0.0f);
        ih = fmaxf(ih, 0.0f);
        float inter = iw * ih;
        float ua = fmaxf(aarea + barea[j] - inter, 1e-8f);
        float iou = __fdividef(inter, ua);
        iou = (blab[j] != -1.0f) ? iou : -1.0f;   // masked invalid -> -1
        if (iou > best) { best = iou; bestj = j; } // strict > == jnp.argmax first-occurrence
    }

    const bool pos = best > 0.5f;
    const bool neg = best < 0.4f;
    const int code = pos ? (int)blab[bestj] : (neg ? -2 : -1);
    labels[(size_t)b * N + n] = (signed char)code;

    float np = 0.0f, rl = 0.0f;
    if (pos) {
        np = 1.0f;
        const float gx1 = bx1[bestj], gy1 = by1[bestj], gx2 = bx2[bestj], gy2 = by2[bestj];
        float gw = gx2 - gx1, gh = gy2 - gy1;
        const float gcx = gx1 + 0.5f * gw, gcy = gy1 + 0.5f * gh; // centers from UNclipped wh
        gw = fmaxf(gw, 1.0f);
        gh = fmaxf(gh, 1.0f);
        const float aw = ax2 - ax1, ah = ay2 - ay1;
        const float acx = ax1 + 0.5f * aw, acy = ay1 + 0.5f * ah;
        const float t0 = ((gcx - acx) / aw) / 0.1f;
        const float t1 = ((gcy - acy) / ah) / 0.1f;
        const float t2 = logf(gw / aw) / 0.2f;
        const float t3 = logf(gh / ah) / 0.2f;
        const float4 rv = reinterpret_cast<const float4*>(regs)[(size_t)b * N + n];
        const float d0 = fabsf(t0 - rv.x), d1 = fabsf(t1 - rv.y);
        const float d2 = fabsf(t2 - rv.z), d3 = fabsf(t3 - rv.w);
        auto sl1 = [](float d) { return d < F_BETA ? 4.5f * d * d : d - (0.5f / 9.0f); };
        rl = sl1(d0) + sl1(d1) + sl1(d2) + sl1(d3);
    }

    np = waveReduceSum(np);
    rl = waveReduceSum(rl);
    __shared__ float s_np[4], s_rl[4];
    const int wave = threadIdx.x >> 6, lane = threadIdx.x & 63;
    if (lane == 0) { s_np[wave] = np; s_rl[wave] = rl; }
    __syncthreads();
    if (threadIdx.x == 0) {
        atomicAdd(&accum[b], s_np[0] + s_np[1] + s_np[2] + s_np[3]);
        atomicAdd(&accum[8 + b], s_rl[0] + s_rl[1] + s_rl[2] + s_rl[3]);
    }
}

// -------------------- Kernel 2: focal classification loss (HBM-bound) ----------
// grid: (GX, B), block: 256; float4 grid-stride over one image's N*C floats
__global__ __launch_bounds__(256) void cls_kernel(
    const float* __restrict__ cls,            // [B,N,C]
    const signed char* __restrict__ labels,   // [B*N]
    float* __restrict__ accum)
{
    const int b = blockIdx.y;
    const float4* __restrict__ cp =
        reinterpret_cast<const float4*>(cls + (size_t)b * N * C);
    const signed char* __restrict__ lp = labels + (size_t)b * N;
    constexpr int TOTAL4 = N * C / 4;   // 1,310,720 float4 per image (C=80 -> 20/anchor)

    float acc = 0.0f;
    const int stride = gridDim.x * blockDim.x;
    for (int f = blockIdx.x * blockDim.x + threadIdx.x; f < TOTAL4; f += stride) {
        const int n = f / 20;               // magic-mul division by constant
        const int c0 = (f - n * 20) * 4;
        const int code = lp[n];
        if (code != -1) {                   // ignore anchors contribute 0 (and skip load)
            const float4 v = cp[f];
            const float vv[4] = {v.x, v.y, v.z, v.w};
            #pragma unroll
            for (int k = 0; k < 4; ++k) {
                const float x = fminf(fmaxf(vv[k], F_EPS), 1.0f - F_EPS);
                const bool p = (code == c0 + k);
                const float fw = p ? 1.0f - x : x;
                const float a = p ? F_ALPHA : 1.0f - F_ALPHA;
                const float y = p ? x : 1.0f - x;
                acc += a * fw * fw * (-__logf(y));
            }
        }
    }

    acc = waveReduceSum(acc);
    __shared__ float s[4];
    const int wave = threadIdx.x >> 6, lane = threadIdx.x & 63;
    if (lane == 0) s[wave] = acc;
    __syncthreads();
    if (threadIdx.x == 0) {
        atomicAdd(&accum[16 + b], s[0] + s[1] + s[2] + s[3]);
    }
}

// -------------------- Kernel 3: final normalization ----------------------------
__global__ void final_kernel(const float* __restrict__ accum, float* __restrict__ out) {
    float total = 0.0f;
    #pragma unroll
    for (int b = 0; b < B; ++b) {
        const float np = accum[b];
        const float rs = accum[8 + b];
        const float cs = accum[16 + b];
        const float cl = cs / fmaxf(np, 1.0f);
        const float rl = (np > 0.0f) ? rs / (fmaxf(np, 1.0f) * 4.0f) : 0.0f;
        total += (cl + rl) * (1.0f / (float)B);
    }
    out[0] = total;
}

extern "C" void kernel_launch(void* const* d_in, const int* in_sizes, int n_in,
                              void* d_out, int out_size, void* d_ws, size_t ws_size,
                              hipStream_t stream) {
    const float* classifications = (const float*)d_in[0]; // [B,N,C]
    const float* regressions     = (const float*)d_in[1]; // [B,N,4]
    const float* anchors         = (const float*)d_in[2]; // [1,N,4]
    const float* annotations     = (const float*)d_in[3]; // [B,M,5]
    float* out = (float*)d_out;

    // Workspace layout: [0, B*N) int8 label codes; then 24 floats of accumulators.
    signed char* labels = (signed char*)d_ws;
    float* accum = (float*)((char*)d_ws + (size_t)B * N); // 512 KiB offset, 16B-aligned

    hipMemsetAsync(accum, 0, 24 * sizeof(float), stream);

    dim3 g1(N / 256, B);
    assign_kernel<<<g1, 256, 0, stream>>>(anchors, regressions, annotations, labels, accum);

    dim3 g2(512, B);  // 4096 blocks total; ~10 float4 per thread
    cls_kernel<<<g2, 256, 0, stream>>>(classifications, labels, accum);

    final_kernel<<<1, 1, 0, stream>>>(accum, out);
}

// Round 2
// 65.434 us; speedup vs baseline: 2.0726x; 2.0726x over previous
//
#include <hip/hip_runtime.h>
#include <math.h>

// Problem constants (from setup_inputs)
constexpr int B = 8, N = 65536, C = 80, M = 64;
constexpr int APB = 256;        // anchors per block
constexpr int BLK = N / APB;    // 256 blocks per image
constexpr float F_ALPHA = 0.25f;
constexpr float F_EPS = 1e-4f;
constexpr float F_BETA = 1.0f / 9.0f;

__device__ __forceinline__ float waveReduceSum(float v) {
    #pragma unroll
    for (int off = 32; off > 0; off >>= 1) v += __shfl_down(v, off, 64);
    return v;
}

// One block = 256 anchors of one image.
// Phase 1: IoU assignment (one anchor per thread, GT boxes in LDS) + reg loss.
// Phase 2: focal cls loss over the block's 256x80 floats, codes from LDS.
// Each block writes ONE float4 partial (num_pos, reg_sum, cls_sum, 0) -> no
// atomics, no zero-init, fully deterministic.
__global__ __launch_bounds__(256) void fused_kernel(
    const float* __restrict__ anchors,   // [N,4]
    const float* __restrict__ regs,      // [B,N,4]
    const float* __restrict__ ann,       // [B,M,5]
    const float* __restrict__ cls,       // [B,N,C]
    float4* __restrict__ partials)       // [B*BLK]
{
    const int b = blockIdx.y;
    const int n0 = blockIdx.x * APB;
    const int tid = threadIdx.x;

    __shared__ float4 sbox[M];    // x1,y1,x2,y2
    __shared__ float2 sal[M];     // area, label
    __shared__ int    scode[APB]; // pos->class, neg->-2, ignore->-1
    __shared__ float  swsum[3][4];

    if (tid < M) {
        const float* a = ann + (size_t)(b * M + tid) * 5;
        const float x1 = a[0], y1 = a[1], x2 = a[2], y2 = a[3], lb = a[4];
        sbox[tid] = make_float4(x1, y1, x2, y2);
        sal[tid] = make_float2((x2 - x1) * (y2 - y1), lb);
    }
    __syncthreads();

    // ---------------- phase 1: assignment ----------------
    const int n = n0 + tid;
    const float4 av = reinterpret_cast<const float4*>(anchors)[n];
    const float aarea = (av.z - av.x) * (av.w - av.y);

    float best = -2.0f;
    int bestj = 0;
    #pragma unroll 8
    for (int j = 0; j < M; ++j) {
        const float4 bb = sbox[j];
        const float2 al = sal[j];
        const float iw = fmaxf(fminf(av.z, bb.z) - fmaxf(av.x, bb.x), 0.0f);
        const float ih = fmaxf(fminf(av.w, bb.w) - fmaxf(av.y, bb.y), 0.0f);
        const float inter = iw * ih;
        const float ua = fmaxf(aarea + al.x - inter, 1e-8f);
        float iou = __fdividef(inter, ua);
        iou = (al.y != -1.0f) ? iou : -1.0f;      // invalid GT -> -1
        if (iou > best) { best = iou; bestj = j; } // strict > == argmax first-occurrence
    }
    const bool pos = best > 0.5f;
    const bool neg = best < 0.4f;
    const int code = pos ? (int)sal[bestj].y : (neg ? -2 : -1);
    scode[tid] = code;

    float np = 0.0f, rl = 0.0f;
    if (pos) {
        np = 1.0f;
        const float4 g = sbox[bestj];
        float gw = g.z - g.x, gh = g.w - g.y;
        const float gcx = g.x + 0.5f * gw, gcy = g.y + 0.5f * gh; // centers from UNclipped wh
        gw = fmaxf(gw, 1.0f);
        gh = fmaxf(gh, 1.0f);
        const float aw = av.z - av.x, ah = av.w - av.y;
        const float acx = av.x + 0.5f * aw, acy = av.y + 0.5f * ah;
        const float t0 = ((gcx - acx) / aw) / 0.1f;
        const float t1 = ((gcy - acy) / ah) / 0.1f;
        const float t2 = logf(gw / aw) / 0.2f;
        const float t3 = logf(gh / ah) / 0.2f;
        const float4 rv = reinterpret_cast<const float4*>(regs)[(size_t)b * N + n];
        const float d0 = fabsf(t0 - rv.x), d1 = fabsf(t1 - rv.y);
        const float d2 = fabsf(t2 - rv.z), d3 = fabsf(t3 - rv.w);
        auto sl1 = [](float d) { return d < F_BETA ? 4.5f * d * d : d - (0.5f / 9.0f); };
        rl = sl1(d0) + sl1(d1) + sl1(d2) + sl1(d3);
    }

    np = waveReduceSum(np);
    rl = waveReduceSum(rl);
    const int wave = tid >> 6, lane = tid & 63;
    if (lane == 0) { swsum[0][wave] = np; swsum[1][wave] = rl; }
    __syncthreads(); // publishes scode + swsum

    // ---------------- phase 2: focal cls loss ----------------
    // Block's slice: APB*C floats = 5120 float4, contiguous, 20 per thread.
    const float4* __restrict__ cp =
        reinterpret_cast<const float4*>(cls) + ((size_t)b * N + n0) * (C / 4);
    float acc = 0.0f;
    #pragma unroll 4
    for (int k = 0; k < APB * C / 4 / 256; ++k) {  // 20 iterations
        const int f = k * 256 + tid;
        const int nl = f / 20;                     // local anchor (20 float4 each)
        const int c0 = (f - nl * 20) * 4;
        const int code2 = scode[nl];
        if (code2 != -1) {                         // ignore anchors: 0 (skip load)
            const float4 v = cp[f];
            const float vv[4] = {v.x, v.y, v.z, v.w};
            #pragma unroll
            for (int q = 0; q < 4; ++q) {
                const float x = fminf(fmaxf(vv[q], F_EPS), 1.0f - F_EPS);
                const bool p = (code2 == c0 + q);
                const float fw = p ? 1.0f - x : x;
                const float a = p ? F_ALPHA : 1.0f - F_ALPHA;
                const float y = p ? x : 1.0f - x;
                acc += a * fw * fw * (-__logf(y));
            }
        }
    }
    acc = waveReduceSum(acc);
    if (lane == 0) swsum[2][wave] = acc;
    __syncthreads();

    if (tid == 0) {
        float4 r;
        r.x = swsum[0][0] + swsum[0][1] + swsum[0][2] + swsum[0][3];
        r.y = swsum[1][0] + swsum[1][1] + swsum[1][2] + swsum[1][3];
        r.z = swsum[2][0] + swsum[2][1] + swsum[2][2] + swsum[2][3];
        r.w = 0.0f;
        partials[b * BLK + blockIdx.x] = r;
    }
}

// One wave per image reduces its 256 block-partials, then thread 0 means.
__global__ __launch_bounds__(512) void final_kernel(
    const float4* __restrict__ partials, float* __restrict__ out)
{
    const int wave = threadIdx.x >> 6, lane = threadIdx.x & 63;
    __shared__ float simg[8];

    float np = 0.0f, rl = 0.0f, cl = 0.0f;
    for (int k = lane; k < BLK; k += 64) {
        const float4 p = partials[wave * BLK + k];
        np += p.x; rl += p.y; cl += p.z;
    }
    np = waveReduceSum(np);
    rl = waveReduceSum(rl);
    cl = waveReduceSum(cl);
    if (lane == 0) {
        const float c = cl / fmaxf(np, 1.0f);
        const float r = (np > 0.0f) ? rl / (fmaxf(np, 1.0f) * 4.0f) : 0.0f;
        simg[wave] = c + r;
    }
    __syncthreads();
    if (threadIdx.x == 0) {
        float t = 0.0f;
        #pragma unroll
        for (int b2 = 0; b2 < B; ++b2) t += simg[b2];
        out[0] = t * (1.0f / (float)B);
    }
}

extern "C" void kernel_launch(void* const* d_in, const int* in_sizes, int n_in,
                              void* d_out, int out_size, void* d_ws, size_t ws_size,
                              hipStream_t stream) {
    const float* classifications = (const float*)d_in[0]; // [B,N,C]
    const float* regressions     = (const float*)d_in[1]; // [B,N,4]
    const float* anchors         = (const float*)d_in[2]; // [1,N,4]
    const float* annotations     = (const float*)d_in[3]; // [B,M,5]
    float* out = (float*)d_out;

    float4* partials = (float4*)d_ws; // B*BLK = 2048 float4 = 32 KiB

    dim3 g(BLK, B);
    fused_kernel<<<g, 256, 0, stream>>>(anchors, regressions, annotations,
                                        classifications, partials);
    final_kernel<<<1, 512, 0, stream>>>(partials, out);
}

// Round 4
// 64.932 us; speedup vs baseline: 2.0887x; 1.0077x over previous
//
#include <hip/hip_runtime.h>
#include <math.h>

// Problem constants (from setup_inputs)
constexpr int B = 8, N = 65536, C = 80, M = 64;
constexpr int APB = 256;          // anchors per block (64 per wave)
constexpr int BPI = N / APB;      // 256 blocks per image
constexpr int K4 = C / 4;         // 20 float4 per anchor
constexpr float F_ALPHA = 0.25f;
constexpr float F_EPS = 1e-4f;
constexpr float F_BETA = 1.0f / 9.0f;

__device__ __forceinline__ float waveReduceSum(float v) {
    #pragma unroll
    for (int off = 32; off > 0; off >>= 1) v += __shfl_down(v, off, 64);
    return v;
}

// One block = 256 anchors (4 waves x 64). Per wave: issue the 20 coalesced
// float4 loads of its own 64x80 cls chunk FIRST (pure, no deps), then do the
// IoU assignment for each lane's anchor while loads are in flight, then the
// focal sweep consuming the registers, with per-float4 codes via __shfl from
// the owning lane. No mid-kernel barrier -> assignment VALU hides under the
// HBM stream. Block writes one float4 partial (np, rl, cl, 0).
__global__ __launch_bounds__(256) void fused_kernel(
    const float* __restrict__ anchors,   // [N,4]
    const float* __restrict__ regs,      // [B,N,4]
    const float* __restrict__ ann,       // [B,M,5]
    const float* __restrict__ cls,       // [B,N,C]
    float4* __restrict__ partials)       // [B*BPI]
{
    const int b = blockIdx.y;
    const int n0 = blockIdx.x * APB;
    const int tid = threadIdx.x;
    const int wave = tid >> 6, lane = tid & 63;
    const int n = n0 + tid;              // this thread's anchor

    __shared__ float4 sbox[M];           // x1,y1,x2,y2
    __shared__ float2 sal[M];            // area, label
    __shared__ float  swsum[3][4];

    if (tid < M) {
        const float* a = ann + (size_t)(b * M + tid) * 5;
        const float x1 = a[0], y1 = a[1], x2 = a[2], y2 = a[3], lb = a[4];
        sbox[tid] = make_float4(x1, y1, x2, y2);
        sal[tid] = make_float2((x2 - x1) * (y2 - y1), lb);
    }
    __syncthreads();

    // ---- issue the wave's 20 coalesced cls loads (1 KB per instruction) ----
    const float4* __restrict__ cpw =
        reinterpret_cast<const float4*>(cls) + ((size_t)b * N + n0 + wave * 64) * K4;
    float4 v[K4];
    #pragma unroll
    for (int k = 0; k < K4; ++k) v[k] = cpw[k * 64 + lane];

    // ---- IoU assignment for own anchor (overlaps the loads above) ----------
    const float4 av = reinterpret_cast<const float4*>(anchors)[n];
    const float aarea = (av.z - av.x) * (av.w - av.y);
    float best = -2.0f;
    int bestj = 0;
    #pragma unroll 8
    for (int j = 0; j < M; ++j) {
        const float4 bb = sbox[j];
        const float2 al = sal[j];
        const float iw = fmaxf(fminf(av.z, bb.z) - fmaxf(av.x, bb.x), 0.0f);
        const float ih = fmaxf(fminf(av.w, bb.w) - fmaxf(av.y, bb.y), 0.0f);
        const float inter = iw * ih;
        const float ua = fmaxf(aarea + al.x - inter, 1e-8f);
        float iou = __fdividef(inter, ua);
        iou = (al.y != -1.0f) ? iou : -1.0f;       // invalid GT -> -1
        if (iou > best) { best = iou; bestj = j; } // strict > == argmax first-occ
    }
    const bool pos = best > 0.5f;
    const bool neg = best < 0.4f;
    const int code = pos ? (int)sal[bestj].y : (neg ? -2 : -1);

    float np = 0.0f, rl = 0.0f;
    if (pos) {
        np = 1.0f;
        const float4 g = sbox[bestj];
        float gw = g.z - g.x, gh = g.w - g.y;
        const float gcx = g.x + 0.5f * gw, gcy = g.y + 0.5f * gh;
        gw = fmaxf(gw, 1.0f);
        gh = fmaxf(gh, 1.0f);
        const float aw = av.z - av.x, ah = av.w - av.y;
        const float acx = av.x + 0.5f * aw, acy = av.y + 0.5f * ah;
        const float t0 = ((gcx - acx) / aw) / 0.1f;
        const float t1 = ((gcy - acy) / ah) / 0.1f;
        const float t2 = logf(gw / aw) / 0.2f;
        const float t3 = logf(gh / ah) / 0.2f;
        const float4 rv = reinterpret_cast<const float4*>(regs)[(size_t)b * N + n];
        const float d0 = fabsf(t0 - rv.x), d1 = fabsf(t1 - rv.y);
        const float d2 = fabsf(t2 - rv.z), d3 = fabsf(t3 - rv.w);
        auto sl1 = [](float d) { return d < F_BETA ? 4.5f * d * d : d - (0.5f / 9.0f); };
        rl = sl1(d0) + sl1(d1) + sl1(d2) + sl1(d3);
    }

    // ---- focal sweep: consume the 20 registers, codes via shuffle ----------
    float a0 = 0.0f, a1 = 0.0f, a2 = 0.0f, a3 = 0.0f;
    #pragma unroll
    for (int k = 0; k < K4; ++k) {
        const int f = k * 64 + lane;
        const int nl = f / 20;                     // owning lane (0..63)
        const int c0 = (f - nl * 20) * 4;
        const int cd = __shfl(code, nl, 64);
        const bool ign = (cd == -1);
        const float aneg = ign ? 0.0f : (1.0f - F_ALPHA);
        const float apos = ign ? 0.0f : F_ALPHA;
        const float vv[4] = {v[k].x, v[k].y, v[k].z, v[k].w};
        float* accp[4] = {&a0, &a1, &a2, &a3};
        #pragma unroll
        for (int q = 0; q < 4; ++q) {
            const float x = fminf(fmaxf(vv[q], F_EPS), 1.0f - F_EPS);
            const float one = 1.0f - x;
            const bool p = (cd == c0 + q);
            const float fw = p ? one : x;
            const float y = p ? x : one;
            const float a = p ? apos : aneg;
            *accp[q] = fmaf(a * fw * fw, -__logf(y), *accp[q]);
        }
    }

    // ---- block reduce, one partial per block --------------------------------
    np = waveReduceSum(np);
    rl = waveReduceSum(rl);
    float cl = waveReduceSum((a0 + a1) + (a2 + a3));
    if (lane == 0) { swsum[0][wave] = np; swsum[1][wave] = rl; swsum[2][wave] = cl; }
    __syncthreads();
    if (tid == 0) {
        float4 r;
        r.x = swsum[0][0] + swsum[0][1] + swsum[0][2] + swsum[0][3];
        r.y = swsum[1][0] + swsum[1][1] + swsum[1][2] + swsum[1][3];
        r.z = swsum[2][0] + swsum[2][1] + swsum[2][2] + swsum[2][3];
        r.w = 0.0f;
        partials[b * BPI + blockIdx.x] = r;
    }
}

// One wave per image reduces its 256 block-partials, then thread 0 means.
__global__ __launch_bounds__(512) void final_kernel(
    const float4* __restrict__ partials, float* __restrict__ out)
{
    const int wave = threadIdx.x >> 6, lane = threadIdx.x & 63;
    __shared__ float simg[8];

    float np = 0.0f, rl = 0.0f, cl = 0.0f;
    for (int k = lane; k < BPI; k += 64) {
        const float4 p = partials[wave * BPI + k];
        np += p.x; rl += p.y; cl += p.z;
    }
    np = waveReduceSum(np);
    rl = waveReduceSum(rl);
    cl = waveReduceSum(cl);
    if (lane == 0) {
        const float c = cl / fmaxf(np, 1.0f);
        const float r = (np > 0.0f) ? rl / (fmaxf(np, 1.0f) * 4.0f) : 0.0f;
        simg[wave] = c + r;
    }
    __syncthreads();
    if (threadIdx.x == 0) {
        float t = 0.0f;
        #pragma unroll
        for (int b2 = 0; b2 < B; ++b2) t += simg[b2];
        out[0] = t * (1.0f / (float)B);
    }
}

extern "C" void kernel_launch(void* const* d_in, const int* in_sizes, int n_in,
                              void* d_out, int out_size, void* d_ws, size_t ws_size,
                              hipStream_t stream) {
    const float* classifications = (const float*)d_in[0]; // [B,N,C]
    const float* regressions     = (const float*)d_in[1]; // [B,N,4]
    const float* anchors         = (const float*)d_in[2]; // [1,N,4]
    const float* annotations     = (const float*)d_in[3]; // [B,M,5]
    float* out = (float*)d_out;
    float4* partials = (float4*)d_ws;                     // B*BPI = 2048 float4

    dim3 g(BPI, B);
    fused_kernel<<<g, 256, 0, stream>>>(anchors, regressions, annotations,
                                        classifications, partials);
    final_kernel<<<1, 512, 0, stream>>>(partials, out);
}